// Round 3
// baseline (276.437 us; speedup 1.0000x reference)
//
#include <hip/hip_runtime.h>
#include <hip/hip_bf16.h>

// Problem constants (fixed by reference setup_inputs)
#define M_DIM 32
#define I_DIM 7168
#define O_DIM 18432
#define SW    56      // I_DIM / 128 (scale row stride)
#define BN    64      // N-cols per block (2 waves x 32)
#define NT    288     // O_DIM / BN
#define KC    14      // split-K factor: 7168/14 = 512 = 4 aligned scale blocks
#define KCHUNK 512    // I_DIM / KC

typedef __attribute__((ext_vector_type(4)))  float  f32x4;   // clang-native: ok for nontemporal builtins
typedef __attribute__((ext_vector_type(8)))  __bf16 bf16x8;
typedef __attribute__((ext_vector_type(16))) float  f32x16;

__global__ __launch_bounds__(128, 8) void fp8lin_gemm(
    const float* __restrict__ x,      // [32, 7168]
    const float* __restrict__ w,      // [18432, 7168]
    const float* __restrict__ s,      // [144, 56]
    float* __restrict__ out) {        // [32, 18432], pre-zeroed
  const int bid   = blockIdx.x;
  const int ntile = bid % NT;        // consecutive blocks -> consecutive O tiles (same kc)
  const int kc    = bid / NT;
  const int wid   = threadIdx.x >> 6;
  const int lane  = threadIdx.x & 63;
  const int r     = lane & 31;       // A row (m) / B col offset
  const int g     = lane >> 5;       // k-group: k = g*8 + j

  const int o0 = ntile * BN + wid * 32;
  const int sbase = (o0 >> 7) * SW;  // all 32 cols share one 128-block of scales

  const float* __restrict__ xrow = x + (size_t)r * I_DIM;
  const float* __restrict__ wrow = w + (size_t)(o0 + r) * I_DIM;

  f32x16 acc;
#pragma unroll
  for (int i = 0; i < 16; ++i) acc[i] = 0.0f;

  const int kbeg = kc * KCHUNK;
  const int kend = kbeg + KCHUNK;

#pragma unroll 2
  for (int k0 = kbeg; k0 < kend; k0 += 16) {
    const int kb = k0 + g * 8;
    const f32x4 a0 = *reinterpret_cast<const f32x4*>(xrow + kb);
    const f32x4 a1 = *reinterpret_cast<const f32x4*>(xrow + kb + 4);
    const f32x4 b0 = __builtin_nontemporal_load(
        reinterpret_cast<const f32x4*>(wrow + kb));
    const f32x4 b1 = __builtin_nontemporal_load(
        reinterpret_cast<const f32x4*>(wrow + kb + 4));
    const float  sc = s[sbase + (k0 >> 7)];   // wave-uniform -> s_load

    bf16x8 au, bu;
    au[0] = (__bf16)a0[0]; au[1] = (__bf16)a0[1];
    au[2] = (__bf16)a0[2]; au[3] = (__bf16)a0[3];
    au[4] = (__bf16)a1[0]; au[5] = (__bf16)a1[1];
    au[6] = (__bf16)a1[2]; au[7] = (__bf16)a1[3];
    bu[0] = (__bf16)(b0[0] * sc); bu[1] = (__bf16)(b0[1] * sc);
    bu[2] = (__bf16)(b0[2] * sc); bu[3] = (__bf16)(b0[3] * sc);
    bu[4] = (__bf16)(b1[0] * sc); bu[5] = (__bf16)(b1[1] * sc);
    bu[6] = (__bf16)(b1[2] * sc); bu[7] = (__bf16)(b1[3] * sc);

    acc = __builtin_amdgcn_mfma_f32_32x32x16_bf16(au, bu, acc, 0, 0, 0);
  }

  // C/D layout (32x32, verified m74/m101): col = lane&31, row = (reg&3) + 8*(reg>>2) + 4*(lane>>5)
  float* __restrict__ op = out + (o0 + r);
#pragma unroll
  for (int reg = 0; reg < 16; ++reg) {
    const int row = (reg & 3) + 8 * (reg >> 2) + 4 * g;
    __hip_atomic_fetch_add(op + (size_t)row * O_DIM, acc[reg],
                           __ATOMIC_RELAXED, __HIP_MEMORY_SCOPE_AGENT);
  }
}

extern "C" void kernel_launch(void* const* d_in, const int* in_sizes, int n_in,
                              void* d_out, int out_size, void* d_ws, size_t ws_size,
                              hipStream_t stream) {
  const float* x = (const float*)d_in[0];
  const float* w = (const float*)d_in[1];
  const float* s = (const float*)d_in[2];
  float* out = (float*)d_out;

  // Split-K accumulates with atomics; output must start at zero every call.
  (void)hipMemsetAsync(out, 0, (size_t)out_size * sizeof(float), stream);

  dim3 grid(NT * KC);   // 4032 blocks = 15.75 per CU -> ~31.5 waves/CU, all resident
  dim3 block(128);      // 2 waves
  fp8lin_gemm<<<grid, block, 0, stream>>>(x, w, s, out);
}

// Round 4
// 108.645 us; speedup vs baseline: 2.5444x; 2.5444x over previous
//
#include <hip/hip_runtime.h>
#include <hip/hip_bf16.h>

// Problem constants (fixed by reference setup_inputs)
#define I_DIM  7168
#define O_DIM  18432
#define SW     56      // I_DIM/128 (scale row stride)
#define BN     128     // O rows per block tile (= exactly one scale block)
#define BK     64      // K floats per tile (never straddles a 128-scale block)
#define ROWS   160     // 128 W rows + 32 x rows staged per tile
#define NTO    144     // O_DIM/BN
#define KC     16      // split-K
#define KCHUNK 448     // I_DIM/KC (multiple of BK; kc*448 % 128 in {0,64})
#define NTILES 7       // KCHUNK/BK

typedef float  f32x4  __attribute__((ext_vector_type(4)));
typedef float  f32x16 __attribute__((ext_vector_type(16)));
typedef __bf16 bf16x8 __attribute__((ext_vector_type(8)));
typedef __bf16 bf16x4 __attribute__((ext_vector_type(4)));

__global__ __launch_bounds__(256, 4) void fp8lin_gemm(
    const float* __restrict__ x,      // [32, 7168]
    const float* __restrict__ w,      // [18432, 7168]
    const float* __restrict__ s,      // [144, 56]
    float* __restrict__ out) {        // [32, 18432], pre-zeroed
  // Two staging buffers: [ROWS][BK] bf16, XOR-swizzled (byte ^= (row&7)<<4).
  __shared__ __bf16 lds[2][ROWS * BK];   // 2 x 20.5 KB = 41 KB -> 4 blocks/CU

  const int tid  = threadIdx.x;
  const int wid  = tid >> 6;
  const int lane = tid & 63;
  const int r    = lane & 31;       // MFMA row/col index
  const int g    = lane >> 5;       // k-group

  const int bid = blockIdx.x;
  const int ot  = bid % NTO;        // consecutive blocks -> consecutive O tiles
  const int kc  = bid / NTO;
  const int o0  = ot * BN;
  const int k0b = kc * KCHUNK;

  // Staging coords: round j covers tile floats [j*1024, (j+1)*1024).
  // Thread t: row = j*16 + (t>>4), col = (t&15)*4  -> wave reads 1KB contiguous.
  const int srow = tid >> 4;          // 0..15
  const int scol = (tid & 15) * 4;    // float col within BK

  f32x4 L[10];   // held global loads (40 VGPRs), static-indexed only

  auto issue = [&](int t) {
    const int kk = k0b + t * BK;
#pragma unroll
    for (int j = 0; j < 10; ++j) {
      const int row = j * 16 + srow;   // 0..159
      const float* p = (j < 8)
          ? (w + (size_t)(o0 + row) * I_DIM + kk + scol)     // W rows 0..127
          : (x + (size_t)(row - 128) * I_DIM + kk + scol);   // x rows 128..159
      L[j] = *reinterpret_cast<const f32x4*>(p);
    }
  };

  auto writeb = [&](int buf, float sc) {
    char* base = (char*)&lds[buf][0];
#pragma unroll
    for (int j = 0; j < 10; ++j) {
      const int row = j * 16 + srow;
      const float scale = (j < 8) ? sc : 1.0f;   // x rows unscaled
      bf16x4 v;
      v[0] = (__bf16)(L[j][0] * scale);
      v[1] = (__bf16)(L[j][1] * scale);
      v[2] = (__bf16)(L[j][2] * scale);
      v[3] = (__bf16)(L[j][3] * scale);
      int byte = row * (BK * 2) + scol * 2;      // [row][col] bf16, 128 B rows
      byte ^= ((row & 7) << 4);                  // T2 swizzle (write side)
      *reinterpret_cast<bf16x4*>(base + byte) = v;
    }
  };

  f32x16 acc;
#pragma unroll
  for (int i = 0; i < 16; ++i) acc[i] = 0.0f;

  const int xrow = 128 + r;          // x staged at tile rows 128..159
  const int wrow = wid * 32 + r;     // this wave's 32 W rows
  const int xswz = (xrow & 7) << 4;
  const int wswz = (wrow & 7) << 4;

  issue(0);
#pragma unroll
  for (int t = 0; t < NTILES; ++t) {
    const float sc = s[ot * SW + ((k0b + t * BK) >> 7)];  // block-uniform
    const int buf = t & 1;
    writeb(buf, sc);
    if (t + 1 < NTILES) issue(t + 1);   // prefetch stays in flight across barrier
    asm volatile("s_waitcnt lgkmcnt(0)" ::: "memory");  // ds_writes visible
    __builtin_amdgcn_s_barrier();                        // raw: no vmcnt drain
    __builtin_amdgcn_sched_barrier(0);                   // pin ds_reads below
    const char* base = (const char*)&lds[buf][0];
#pragma unroll
    for (int kb = 0; kb < BK; kb += 16) {
      const int cb = kb * 2 + g * 16;
      bf16x8 a = *reinterpret_cast<const bf16x8*>(base + ((xrow * 128 + cb) ^ xswz));
      bf16x8 b = *reinterpret_cast<const bf16x8*>(base + ((wrow * 128 + cb) ^ wswz));
      acc = __builtin_amdgcn_mfma_f32_32x32x16_bf16(a, b, acc, 0, 0, 0);
    }
    // One barrier/tile is sufficient: barrier[t] transitively separates
    // compute(buf)[t-1] from write(buf)[t+1] (lgkmcnt(0) drains reads too).
  }

  // C/D layout (32x32, verified m74/m101): col=lane&31, row=(reg&3)+8*(reg>>2)+4*g
  float* op = out + o0 + wid * 32 + r;
#pragma unroll
  for (int reg = 0; reg < 16; ++reg) {
    const int row = (reg & 3) + 8 * (reg >> 2) + 4 * g;
    __hip_atomic_fetch_add(op + (size_t)row * O_DIM, acc[reg],
                           __ATOMIC_RELAXED, __HIP_MEMORY_SCOPE_AGENT);
  }
}

extern "C" void kernel_launch(void* const* d_in, const int* in_sizes, int n_in,
                              void* d_out, int out_size, void* d_ws, size_t ws_size,
                              hipStream_t stream) {
  const float* x = (const float*)d_in[0];
  const float* w = (const float*)d_in[1];
  const float* s = (const float*)d_in[2];
  float* out = (float*)d_out;

  // Split-K accumulates with atomics; output must start at zero every call.
  (void)hipMemsetAsync(out, 0, (size_t)out_size * sizeof(float), stream);

  dim3 grid(NTO * KC);   // 2304 blocks, 4 blocks/CU resident (LDS-limited)
  dim3 block(256);       // 4 waves
  fp8lin_gemm<<<grid, block, 0, stream>>>(x, w, s, out);
}